// Round 8
// baseline (479.897 us; speedup 1.0000x reference)
//
#include <hip/hip_runtime.h>

#define EPSV 1e-5f

constexpr int CIN = 64, NH = 128, NW = 128, HID = 384, COUT = 64;
constexpr int N1 = HID * CIN;            // 24576
constexpr int N2 = HID * 9;              // 3456
constexpr int NP = N1 + N2 + COUT * HID; // 52608

using bf16x8 = __attribute__((ext_vector_type(8))) short;
using f32x4  = __attribute__((ext_vector_type(4))) float;
using h16x2  = __attribute__((ext_vector_type(2))) _Float16;
using f16x8  = __attribute__((ext_vector_type(8))) _Float16;

__device__ __forceinline__ unsigned short f2bf(float f) {
  unsigned int u = __float_as_uint(f);
  u = (u + 0x7fffu + ((u >> 16) & 1u)) >> 16;
  return (unsigned short)u;
}
__device__ __forceinline__ unsigned int pack2(float a, float b) {
  return (unsigned int)f2bf(a) | ((unsigned int)f2bf(b) << 16);
}
// fp16 helpers: v_cvt_pkrtz_f16_f32 packs 2 f32 -> 2 f16 in ONE instruction.
__device__ __forceinline__ unsigned int pkh2(float a, float b) {
  auto h = __builtin_amdgcn_cvt_pkrtz(a, b);
  return *reinterpret_cast<unsigned int*>(&h);
}
__device__ __forceinline__ unsigned short f2h(float f) {
  _Float16 h = (_Float16)f;
  return *reinterpret_cast<unsigned short*>(&h);
}
__device__ __forceinline__ h16x2 uh2(unsigned int u) {
  return *reinterpret_cast<h16x2*>(&u);
}
__device__ __forceinline__ float clamp6(float v) { return fminf(fmaxf(v, 0.f), 6.f); }

// raw barrier: LDS-visibility only, never drains vmcnt (keeps prefetch in flight)
#define BAR_LDS()                                             \
  do {                                                        \
    asm volatile("s_waitcnt lgkmcnt(0)" ::: "memory");        \
    __builtin_amdgcn_s_barrier();                             \
  } while (0)

// ---------------------------------------------------------------------------
// K0: transpose x [b][c][y][x] f32 -> xT [b][y][x][c] bf16 (8.4 MB, in d_out).
// ---------------------------------------------------------------------------
__global__ __launch_bounds__(256) void k0_transpose(
    const float* __restrict__ x, unsigned short* __restrict__ xT) {
  __shared__ unsigned short xls[64][66];
  const int t = threadIdx.x;
  const int xh = blockIdx.x, y = blockIdx.y, b = blockIdx.z;
#pragma unroll
  for (int it = 0; it < 4; ++it) {
    int i = it * 256 + t;
    int xq = i & 15, c = i >> 4;
    float4 v = *reinterpret_cast<const float4*>(
        &x[((size_t)(b * CIN + c) * NH + y) * NW + xh * 64 + xq * 4]);
    *(unsigned int*)&xls[c][xq * 4]     = pack2(v.x, v.y);
    *(unsigned int*)&xls[c][xq * 4 + 2] = pack2(v.z, v.w);
  }
  __syncthreads();
#pragma unroll
  for (int it = 0; it < 4; ++it) {
    int i = it * 256 + t;
    int cq = i & 15, px = i >> 4;
    ushort4 o;
    o.x = xls[cq * 4 + 0][px];
    o.y = xls[cq * 4 + 1][px];
    o.z = xls[cq * 4 + 2][px];
    o.w = xls[cq * 4 + 3][px];
    *reinterpret_cast<ushort4*>(
        &xT[((size_t)(b * NH + y) * NW + xh * 64 + px) * 64 + cq * 4]) = o;
  }
}

// ---------------------------------------------------------------------------
// K1: per-patch pw1 (bf16 MFMA) + bn1 + relu6 -> h1T [b][y][x][hid] fp16.
// (unchanged from verified round-7 version)
// ---------------------------------------------------------------------------
__global__ __launch_bounds__(256) void k1_pw1(
    const float* __restrict__ w, const unsigned short* __restrict__ xT,
    const float* __restrict__ g1, const float* __restrict__ b1,
    const float* __restrict__ m1, const float* __restrict__ v1,
    unsigned short* __restrict__ h1T) {
  __shared__ unsigned short Wpk[2048 * 8];  // 32 KB packed A-frags

  const unsigned int id = blockIdx.x;
  const int fbq = id & 7;
  const unsigned int rest = id >> 3;
  const int hgrp = rest % 24, q = rest / 24;
  const int fb = q * 8 + fbq;
  const int f = fb & 15, b = fb >> 4;
  const int h0 = hgrp * 16;

  const int t = threadIdx.x;
  const int lane = t & 63, wv = t >> 6;
  const int quad = lane >> 4, nn = lane & 15;
  const int pxi = wv * 16 + nn;

#pragma unroll
  for (int it = 0; it < 8; ++it) {
    int i = it * 256 + t;  // 0..2047
    int gq = i & 3, cp = (i >> 2) & 31, hid = i >> 7;
    const float* wp =
        &w[((size_t)b * NP + (h0 + hid) * CIN + cp * 2) * 256 + f * 16 + gq * 4];
    float4 A  = *reinterpret_cast<const float4*>(wp);
    float4 Bv = *reinterpret_cast<const float4*>(wp + 256);
    int kc = cp >> 4, qd = (cp >> 2) & 3, j = (cp & 3) * 2;
    int hs = hid ^ (2 * qd) ^ gq;
    const float* Af = (const float*)&A;
    const float* Bf = (const float*)&Bv;
#pragma unroll
    for (int k = 0; k < 4; ++k) {
      int g = gq * 4 + k;
      *(unsigned int*)&Wpk[(((g * 2 + kc) * 4 + qd) * 16 + hs) * 8 + j] =
          pack2(Af[k], Bf[k]);
    }
  }

  float iv1[4], sh1[4];
#pragma unroll
  for (int jj = 0; jj < 4; ++jj) {
    int hid = h0 + quad * 4 + jj;
    float iv = g1[hid] * rsqrtf(v1[hid] + EPSV);
    iv1[jj] = iv;
    sh1[jj] = b1[hid] - m1[hid] * iv;
  }
  __syncthreads();  // Wpk ready; read-only below

  const int y = f * 8 + (pxi >> 3);
  const size_t rowbase = ((size_t)b * NH + y) * NW;

  for (int g = 0; g < 16; ++g) {
    const int xc = g * 8 + (pxi & 7);
    const unsigned short* xp = &xT[(rowbase + xc) * 64];
    f32x4 acc = {0.f, 0.f, 0.f, 0.f};
    const int hs = nn ^ (2 * quad) ^ (g >> 2);
#pragma unroll
    for (int kc = 0; kc < 2; ++kc) {
      bf16x8 af = *reinterpret_cast<const bf16x8*>(
          &Wpk[(((g * 2 + kc) * 4 + quad) * 16 + hs) * 8]);
      bf16x8 bfr = *reinterpret_cast<const bf16x8*>(&xp[kc * 32 + quad * 8]);
      acc = __builtin_amdgcn_mfma_f32_16x16x32_bf16(af, bfr, acc, 0, 0, 0);
    }
    uint2 o;
    o.x = pkh2(clamp6(acc[0] * iv1[0] + sh1[0]),
               clamp6(acc[1] * iv1[1] + sh1[1]));
    o.y = pkh2(clamp6(acc[2] * iv1[2] + sh1[2]),
               clamp6(acc[3] * iv1[3] + sh1[3]));
    *reinterpret_cast<uint2*>(&h1T[(rowbase + xc) * HID + h0 + quad * 4]) = o;
  }
}

// ---------------------------------------------------------------------------
// K2 v6: ch pair split by ROWS (4+4) instead of output channels. Block =
// (f,b,gq,ch-rowhalf): 4 rows x 32 cols x ALL 64 co.
//  - dw3 global work HALVED (v3/v5 ch-co-split computed it twice)
//  - halo fetch -40% (6-row tile x2 vs 10-row x2)
//  - LDS 47.8 KB -> 3 blocks/CU (12 waves, 3 barrier groups; v4 showed
//    concurrency > dedup, v4's failure was 1 block/CU lockstep)
// W3p = v4's verified dual-coh layout (16 KB, fp16). Wave = (coh, glh);
// a 64-px half spans 2 patches -> 4 A-frags/chunk, patch = glh*2 + (nt>>1).
// T14 scalar prefetch kept; W3 dests derived from base via ^(k<<4)+k*2048.
// ---------------------------------------------------------------------------
__global__ __launch_bounds__(256, 3) void k2_fused(
    const float* __restrict__ x, const float* __restrict__ w,
    const float* __restrict__ g2, const float* __restrict__ b2v,
    const float* __restrict__ m2, const float* __restrict__ v2,
    const float* __restrict__ g3, const float* __restrict__ b3v,
    const float* __restrict__ m3, const float* __restrict__ v3,
    const unsigned short* __restrict__ h1T, float* __restrict__ out) {
  __shared__ unsigned short tile[6][34][40];   // 15.9 KB h1 halo fp16
  __shared__ unsigned short h2s[128][40];      // 10.0 KB h2 chunk fp16
  __shared__ unsigned short W3p[8192];         // 16 KB A-frags fp16 (2 coh)
  __shared__ unsigned short k2w[4][9][40];     // 2.8 KB dw kernels fp16
  __shared__ float iv2s[HID], sh2s[HID];       // 3 KB          (47.8 KB total)

  const unsigned int id = blockIdx.x;          // 512 blocks
  const int fbq = id & 7;
  const unsigned int rest = id >> 3;
  const int gang = rest & 7, q = rest >> 3;
  const int fb = q * 8 + fbq;
  const int f = fb & 15, b = fb >> 4;
  const int gq = gang >> 1, ch = gang & 1;
  const int c0 = gq * 32;
  const int r0 = f * 8 + ch * 4;               // first output row

  const int t = threadIdx.x;
  const int lane = t & 63, wv = t >> 6;
  const int quad = lane >> 4, nn = lane & 15;
  // MFMA wave roles
  const int glh = wv & 1, coh = wv >> 1;
  // dw3 roles: px p (patch-major: patchq*32 + prt*8 + pct), hid half
  const int p = t & 127, hhalf = t >> 7;
  const int patchq = p >> 5, prt = (p >> 3) & 3, pct = p & 7;

  for (int i = t; i < HID; i += 256) {
    float iv = g2[i] * rsqrtf(v2[i] + EPSV);
    iv2s[i] = iv;
    sh2s[i] = b2v[i] - m2[i] * iv;
  }

  float iv3[2][4], sh3[2][4];
#pragma unroll
  for (int cot = 0; cot < 2; ++cot)
#pragma unroll
    for (int jj = 0; jj < 4; ++jj) {
      int co = coh * 32 + cot * 16 + quad * 4 + jj;
      float iv = g3[co] * rsqrtf(v3[co] + EPSV);
      iv3[cot][jj] = iv;
      sh3[cot][jj] = b3v[co] - m3[co] * iv;
    }

  f32x4 acc[2][4];
#pragma unroll
  for (int cot = 0; cot < 2; ++cot)
#pragma unroll
    for (int nt = 0; nt < 4; ++nt) acc[cot][nt] = (f32x4){0.f, 0.f, 0.f, 0.f};

  // ---- hoisted staging geometry, all SCALAR ----
  // tile halo: 6 rows x 34 cols x 4 hid-quarters = 816 units.
#define TGEOM(IDX, SRC, DST)                                          \
  {                                                                   \
    int qh = (IDX) & 3, pxid = (IDX) >> 2;                            \
    int r = pxid / 34, col = pxid - r * 34;                           \
    int yy = r0 - 1 + r;                                              \
    yy = (yy < 0) ? -yy : ((yy > 127) ? 254 - yy : yy);               \
    int xc = c0 - 1 + col;                                            \
    xc = (xc < 0) ? 1 : ((xc > 127) ? 126 : xc);                      \
    SRC = &h1T[(((size_t)b * NH + yy) * NW + xc) * HID + qh * 8];     \
    DST = &tile[r][col][qh * 8];                                      \
  }
  const unsigned short *ts0, *ts1, *ts2, *ts3;
  unsigned short *td0, *td1, *td2, *td3;
  const bool tac3 = (t < 48);
  TGEOM(t, ts0, td0);
  TGEOM(256 + t, ts1, td1);
  TGEOM(512 + t, ts2, td2);
  {
    int idx3 = tac3 ? (768 + t) : 815;
    TGEOM(idx3, ts3, td3);
  }
#undef TGEOM

  // dw kernels: 288 units (hh*9+tap)
  const int hh1 = t / 9, tap1 = t - hh1 * 9;
  const float* ksrc1 = &w[((size_t)b * NP + N1 + t) * 256 + f * 16 + gq * 4];
  const bool kac2 = (t < 32);
  const int i2k = 256 + t;
  const int hh2 = i2k / 9, tap2 = i2k - hh2 * 9;
  const float* ksrc2 = &w[((size_t)b * NP + N1 + i2k) * 256 + f * 16 + gq * 4];

  // W3 A-frags: 1024 units (64 co x 16 hhp) over 256 thr = 4 slots.
  // dest(k) = (base ^ (k<<4)) + k*2048 bytes into W3p.
  const float *wsrc0, *wsrc1, *wsrc2, *wsrc3;
  unsigned int wb0, wb1, wb2, wb3;
#define W3GEOM(IT, SRC, WB)                                               \
  {                                                                      \
    int i = (IT) * 256 + t;                                              \
    int hhp = i & 15, co = i >> 4; /* co 0..63 */                        \
    SRC = &w[((size_t)b * NP + N1 + N2 + co * HID + hhp * 2) * 256 +     \
             f * 16 + gq * 4];                                           \
    int qd = (hhp * 2) >> 3, j = (hhp * 2) & 7;                          \
    int ch2 = co >> 5, cot = (co >> 4) & 1, cb = co & 15;                \
    int cop0 = cb ^ (2 * qd);                                            \
    WB = (unsigned int)(ch2 * 8192 + (cot * 4 + qd) * 256 + cop0 * 16 +  \
                        j * 2);                                          \
  }
  W3GEOM(0, wsrc0, wb0);
  W3GEOM(1, wsrc1, wb1);
  W3GEOM(2, wsrc2, wb2);
  W3GEOM(3, wsrc3, wb3);
#undef W3GEOM

  uint4 tr0, tr1, tr2, tr3;
  float4 kr1, kr2;
  float4 wA0, wB0, wA1, wB1, wA2, wB2, wA3, wB3;

#define PREFETCH()                                                  \
  do {                                                              \
    tr0 = *reinterpret_cast<const uint4*>(ts0); ts0 += 32;          \
    tr1 = *reinterpret_cast<const uint4*>(ts1); ts1 += 32;          \
    tr2 = *reinterpret_cast<const uint4*>(ts2); ts2 += 32;          \
    if (tac3) tr3 = *reinterpret_cast<const uint4*>(ts3);           \
    ts3 += 32;                                                      \
    kr1 = *reinterpret_cast<const float4*>(ksrc1); ksrc1 += 73728;  \
    if (kac2) kr2 = *reinterpret_cast<const float4*>(ksrc2);        \
    ksrc2 += 73728;                                                 \
    wA0 = *reinterpret_cast<const float4*>(wsrc0);                  \
    wB0 = *reinterpret_cast<const float4*>(wsrc0 + 256);            \
    wsrc0 += 8192;                                                  \
    wA1 = *reinterpret_cast<const float4*>(wsrc1);                  \
    wB1 = *reinterpret_cast<const float4*>(wsrc1 + 256);            \
    wsrc1 += 8192;                                                  \
    wA2 = *reinterpret_cast<const float4*>(wsrc2);                  \
    wB2 = *reinterpret_cast<const float4*>(wsrc2 + 256);            \
    wsrc2 += 8192;                                                  \
    wA3 = *reinterpret_cast<const float4*>(wsrc3);                  \
    wB3 = *reinterpret_cast<const float4*>(wsrc3 + 256);            \
    wsrc3 += 8192;                                                  \
  } while (0)

#define W3WRITE(WB, WA, WV)                                                   \
  do {                                                                        \
    const float* Af = (const float*)&(WA);                                    \
    const float* Bf = (const float*)&(WV);                                    \
    *(unsigned int*)((char*)W3p + (WB))                  = pkh2(Af[0], Bf[0]);\
    *(unsigned int*)((char*)W3p + (((WB) ^ 16) + 2048))  = pkh2(Af[1], Bf[1]);\
    *(unsigned int*)((char*)W3p + (((WB) ^ 32) + 4096))  = pkh2(Af[2], Bf[2]);\
    *(unsigned int*)((char*)W3p + (((WB) ^ 48) + 6144))  = pkh2(Af[3], Bf[3]);\
  } while (0)

  tr3 = (uint4){0u, 0u, 0u, 0u};
  kr2 = (float4){0.f, 0.f, 0.f, 0.f};
  PREFETCH();  // chunk 0

  const h16x2 hz = {(_Float16)0.f, (_Float16)0.f};

  for (int hc = 0; hc < 12; ++hc) {
    const int hb = hc * 32;
    BAR_LDS();  // prev chunk consumers done with tile/W3p/k2w/h2s

    // ---- write staged registers -> LDS ----
    *reinterpret_cast<uint4*>(td0) = tr0;
    *reinterpret_cast<uint4*>(td1) = tr1;
    *reinterpret_cast<uint4*>(td2) = tr2;
    if (tac3) *reinterpret_cast<uint4*>(td3) = tr3;
    k2w[0][tap1][hh1] = f2h(kr1.x);
    k2w[1][tap1][hh1] = f2h(kr1.y);
    k2w[2][tap1][hh1] = f2h(kr1.z);
    k2w[3][tap1][hh1] = f2h(kr1.w);
    if (kac2) {
      k2w[0][tap2][hh2] = f2h(kr2.x);
      k2w[1][tap2][hh2] = f2h(kr2.y);
      k2w[2][tap2][hh2] = f2h(kr2.z);
      k2w[3][tap2][hh2] = f2h(kr2.w);
    }
    W3WRITE(wb0, wA0, wB0);
    W3WRITE(wb1, wA1, wB1);
    W3WRITE(wb2, wA2, wB2);
    W3WRITE(wb3, wA3, wB3);

    BAR_LDS();  // LDS staged for this chunk

    // ---- issue NEXT chunk's loads; they fly under dw3 + MFMA ----
    if (hc < 11) PREFETCH();

    // ---- dw3 (packed fp16 FMA) + bn2 + relu6 -> h2s (1 px, 16 hid) ----
#pragma unroll
    for (int hg2 = 0; hg2 < 2; ++hg2) {
      const int hg = hhalf * 2 + hg2;
      h16x2 d0 = hz, d1 = hz, d2 = hz, d3 = hz;
#pragma unroll
      for (int dy = 0; dy < 3; ++dy)
#pragma unroll
        for (int dx = 0; dx < 3; ++dx) {
          const uint4 tv = *reinterpret_cast<const uint4*>(
              &tile[prt + dy][patchq * 8 + pct + dx][hg * 8]);
          const uint4 kv =
              *reinterpret_cast<const uint4*>(&k2w[patchq][dy * 3 + dx][hg * 8]);
          d0 += uh2(tv.x) * uh2(kv.x);
          d1 += uh2(tv.y) * uh2(kv.y);
          d2 += uh2(tv.z) * uh2(kv.z);
          d3 += uh2(tv.w) * uh2(kv.w);
        }
      const int ha = hb + hg * 8;
      uint4 o4;
      o4.x = pkh2(clamp6((float)d0[0] * iv2s[ha + 0] + sh2s[ha + 0]),
                  clamp6((float)d0[1] * iv2s[ha + 1] + sh2s[ha + 1]));
      o4.y = pkh2(clamp6((float)d1[0] * iv2s[ha + 2] + sh2s[ha + 2]),
                  clamp6((float)d1[1] * iv2s[ha + 3] + sh2s[ha + 3]));
      o4.z = pkh2(clamp6((float)d2[0] * iv2s[ha + 4] + sh2s[ha + 4]),
                  clamp6((float)d2[1] * iv2s[ha + 5] + sh2s[ha + 5]));
      o4.w = pkh2(clamp6((float)d3[0] * iv2s[ha + 6] + sh2s[ha + 6]),
                  clamp6((float)d3[1] * iv2s[ha + 7] + sh2s[ha + 7]));
      *reinterpret_cast<uint4*>(&h2s[p][hg * 8]) = o4;
    }

    BAR_LDS();  // h2s visible

    // ---- pw2 fp16 MFMA: wave (coh, glh); patch = glh*2 + (nt>>1) ----
    {
      const int cop0 = nn ^ (2 * quad);
      const int kp0 = glh * 2, kp1 = glh * 2 + 1;
      f16x8 aA0 = *reinterpret_cast<const f16x8*>(
          &W3p[coh * 4096 + (((kp0 * 2 + 0) * 4 + quad) * 16 + (cop0 ^ kp0)) * 8]);
      f16x8 aB0 = *reinterpret_cast<const f16x8*>(
          &W3p[coh * 4096 + (((kp0 * 2 + 1) * 4 + quad) * 16 + (cop0 ^ kp0)) * 8]);
      f16x8 aA1 = *reinterpret_cast<const f16x8*>(
          &W3p[coh * 4096 + (((kp1 * 2 + 0) * 4 + quad) * 16 + (cop0 ^ kp1)) * 8]);
      f16x8 aB1 = *reinterpret_cast<const f16x8*>(
          &W3p[coh * 4096 + (((kp1 * 2 + 1) * 4 + quad) * 16 + (cop0 ^ kp1)) * 8]);
#pragma unroll
      for (int nt = 0; nt < 4; ++nt) {
        f16x8 bfr = *reinterpret_cast<const f16x8*>(
            &h2s[glh * 64 + nt * 16 + nn][quad * 8]);
        if (nt < 2) {
          acc[0][nt] = __builtin_amdgcn_mfma_f32_16x16x32_f16(aA0, bfr, acc[0][nt], 0, 0, 0);
          acc[1][nt] = __builtin_amdgcn_mfma_f32_16x16x32_f16(aB0, bfr, acc[1][nt], 0, 0, 0);
        } else {
          acc[0][nt] = __builtin_amdgcn_mfma_f32_16x16x32_f16(aA1, bfr, acc[0][nt], 0, 0, 0);
          acc[1][nt] = __builtin_amdgcn_mfma_f32_16x16x32_f16(aB1, bfr, acc[1][nt], 0, 0, 0);
        }
      }
    }
  }

  // ---- epilogue: bn3 + residual ----
  // px p = glh*64 + nt*16 + nn: patch = glh*2+(nt>>1), rt = (nt&1)*2+(nn>>3)
#pragma unroll
  for (int cot = 0; cot < 2; ++cot)
#pragma unroll
    for (int nt = 0; nt < 4; ++nt) {
      int rt_ = (nt & 1) * 2 + (nn >> 3);
      int patch_ = glh * 2 + (nt >> 1);
      int y = r0 + rt_;
      int xc = c0 + patch_ * 8 + (nn & 7);
#pragma unroll
      for (int jj = 0; jj < 4; ++jj) {
        int co = coh * 32 + cot * 16 + quad * 4 + jj;
        size_t adr = ((size_t)(b * COUT + co) * NH + y) * NW + xc;
        out[adr] = acc[cot][nt][jj] * iv3[cot][jj] + sh3[cot][jj] + x[adr];
      }
    }
}

extern "C" void kernel_launch(void* const* d_in, const int* in_sizes, int n_in,
                              void* d_out, int out_size, void* d_ws,
                              size_t ws_size, hipStream_t stream) {
  (void)in_sizes; (void)n_in; (void)out_size; (void)ws_size;
  const float* x  = (const float*)d_in[0];
  const float* w  = (const float*)d_in[1];
  const float* g1 = (const float*)d_in[2];
  const float* b1 = (const float*)d_in[3];
  const float* m1 = (const float*)d_in[4];
  const float* v1 = (const float*)d_in[5];
  const float* g2 = (const float*)d_in[6];
  const float* b2 = (const float*)d_in[7];
  const float* m2 = (const float*)d_in[8];
  const float* v2 = (const float*)d_in[9];
  const float* g3 = (const float*)d_in[10];
  const float* b3 = (const float*)d_in[11];
  const float* m3 = (const float*)d_in[12];
  const float* v3 = (const float*)d_in[13];
  float* out = (float*)d_out;
  unsigned short* h1T = (unsigned short*)d_ws;  // [b][y][x][hid] fp16, 50.3 MB
  unsigned short* xT = (unsigned short*)d_out;  // [b][y][x][c] bf16, 8.4 MB
                                                // (scratch; K2 overwrites out)

  k0_transpose<<<dim3(2, 128, 4), 256, 0, stream>>>(x, xT);
  k1_pw1<<<dim3(1536), 256, 0, stream>>>(w, xT, g1, b1, m1, v1, h1T);
  k2_fused<<<dim3(512), 256, 0, stream>>>(x, w, g2, b2, m2, v2, g3, b3, m3, v3,
                                          h1T, out);
}